// Round 2
// baseline (95.045 us; speedup 1.0000x reference)
//
#include <hip/hip_runtime.h>
#include <hip/hip_bf16.h>

#define EPSW 1e-6f

typedef __attribute__((ext_vector_type(4))) float floatx4;
typedef __attribute__((ext_vector_type(2))) unsigned int uintx2;
typedef __attribute__((ext_vector_type(4))) unsigned int uintx4;
typedef __attribute__((ext_vector_type(8))) short shortx8;   // 8 bf16 (4 VGPRs)

// round-to-nearest-even float -> bf16 bits (finite inputs)
__device__ __forceinline__ unsigned short f2bf(float f) {
    unsigned int u = __float_as_uint(f);
    u = (u + 0x7fffu + ((u >> 16) & 1u)) >> 16;
    return (unsigned short)u;
}

__device__ __forceinline__ float bf2f(unsigned short b) {
    return __uint_as_float((unsigned int)b << 16);
}

__device__ __forceinline__ unsigned int pk2(float lo, float hi) {
    return (unsigned int)f2bf(lo) | ((unsigned int)f2bf(hi) << 16);
}

// async global->LDS DMA, 16B per lane: lane i's 16B land at l + i*16.
__device__ __forceinline__ void gl_lds16(const void* g, void* l) {
    __builtin_amdgcn_global_load_lds(
        (const __attribute__((address_space(1))) unsigned int*)g,
        (__attribute__((address_space(3))) unsigned int*)l, 16, 0, 0);
}

// ---------------------------------------------------------------------------
// prep: 28 blocks x 512 threads.
//   blocks 0..15 : W -> wt bf16, granule (kg,h) at kg*128+h, zero-padded.
//   blocks 16..19: Mt[c][n] = (A@A)[n][c], n-sliced 16 rows per block.
//   blocks 20..27: y[b][n][h] = bias[h]  (atomic-accumulated by gemm_fused).
// ---------------------------------------------------------------------------
__global__ __launch_bounds__(512) void prep(const float* __restrict__ W,
                                            const int* __restrict__ ei,
                                            const float* __restrict__ ew,
                                            const float* __restrict__ bias,
                                            unsigned short* __restrict__ wt,
                                            float* __restrict__ Mt,
                                            float* __restrict__ y) {
    __shared__ float sA[4096 + 128];
    const int bid = blockIdx.x;
    const int t   = threadIdx.x;

    if (bid < 16) {
#pragma unroll
        for (int i = 0; i < 4; ++i) {
            const int G  = bid * 2048 + i * 512 + t;  // 0..32767
            const int kg = G >> 7;
            const int h  = G & 127;
            const int k  = kg * 8;
            floatx4 v0 = (floatx4){0.f, 0.f, 0.f, 0.f};
            floatx4 v1 = (floatx4){0.f, 0.f, 0.f, 0.f};
            if (k < 2000) {  // kg<=249 -> whole granule valid
                v0 = *(const floatx4*)(W + (size_t)h * 2000 + k);
                v1 = *(const floatx4*)(W + (size_t)h * 2000 + k + 4);
            }
            unsigned short* p = wt + ((size_t)kg * 128 + h) * 8;
            p[0] = f2bf(v0.x); p[1] = f2bf(v0.y); p[2] = f2bf(v0.z); p[3] = f2bf(v0.w);
            p[4] = f2bf(v1.x); p[5] = f2bf(v1.y); p[6] = f2bf(v1.z); p[7] = f2bf(v1.w);
        }
    } else if (bid < 20) {
        const int bb = bid - 16;                // 0..3: n-slice [bb*16, bb*16+16)
        float* A    = sA;                       // 4096 f, A[n][k] (row-major)
        float* deg  = sA + 4096;
        float* dinv = deg + 64;
        if (t < 64) deg[t] = 1.0f;              // self-loop pre-added
        for (int i = t; i < 4096; i += 512) A[i] = 0.0f;
        __syncthreads();
        const int* srcp = ei;
        const int* dstp = ei + 4096;
#pragma unroll
        for (int i = 0; i < 8; ++i) {
            const int e = i * 512 + t;
            float w = ew[e];
            w = (w <= 0.0f) ? EPSW : w;
            atomicAdd(&deg[dstp[e]], w);
        }
        __syncthreads();
        if (t < 64) dinv[t] = 1.0f / sqrtf(deg[t]);
        __syncthreads();
#pragma unroll
        for (int i = 0; i < 8; ++i) {
            const int e = i * 512 + t;
            float w = ew[e];
            w = (w <= 0.0f) ? EPSW : w;
            const int s = srcp[e], d = dstp[e];
            atomicAdd(&A[d * 64 + s], dinv[s] * w * dinv[d]);
        }
        if (t < 64) atomicAdd(&A[t * 64 + t], dinv[t] * dinv[t]);
        __syncthreads();
        const int c  = t & 63;
        const int n0 = bb * 16 + (t >> 6);
        const int n1 = n0 + 8;
        float s0 = 0.0f, s1 = 0.0f;
#pragma unroll 8
        for (int k = 0; k < 64; ++k) {
            const float akc = A[k * 64 + c];
            s0 += A[n0 * 64 + k] * akc;
            s1 += A[n1 * 64 + k] * akc;
        }
        Mt[c * 64 + n0] = s0;
        Mt[c * 64 + n1] = s1;
    } else {
        // y = broadcast bias. 8 blocks x 512 thr x 16 float4 = 256K floats.
        const floatx4 bv = *(const floatx4*)(bias + (t & 31) * 4);
#pragma unroll
        for (int i = 0; i < 16; ++i) {
            const int idx4 = (bid - 20) * 8192 + i * 512 + t;
            *(floatx4*)(y + (size_t)idx4 * 4) = bv;
        }
    }
}

// ---------------------------------------------------------------------------
// gemm_fused: 256 blocks x 256 threads (4 waves). bid: ks = bid>>5 (K-slice
// of 256 = 32 kg), b = bid&31 (batch; rows b*64..b*64+63 = that batch's 64
// nodes).
// Main loop identical to r1's gemm_lds: fused x fp32->bf16 A-staging (reg),
// wt DMA B-staging, double-buffered, 4 chunks of BK=64, 16 MFMA/chunk.
// NEW epilogue (replaces zp + apply_M kernel): apply the 2-hop mixing matrix
// M (64x64) to the block's partial z (64 nodes x 128 h) in-block via
// error-split bf16 MFMA (Mhi*zhi + Mhi*zlo + Mlo*zhi; residual ~1e-5 rel),
// then atomicAdd into bias-pre-initialized y. M granules (hi/lo) built once
// per block from fp32 Mt during the chunk-0 DMA latency window.
// LDS: staging 2x24 KB (z-granule scratch aliases it in the epilogue) +
// 16 KB M granules = 64 KB.
// ---------------------------------------------------------------------------
__global__ __launch_bounds__(256) void gemm_fused(
        const float* __restrict__ x,
        const unsigned short* __restrict__ wt,
        const float* __restrict__ Mtg,
        float* __restrict__ y) {
    __shared__ __align__(16) unsigned char smem[2][24576];
    __shared__ __align__(16) unsigned char mg[16384];   // Mhi | Mlo granules
    const int t    = threadIdx.x;
    const int wave = t >> 6, lane = t & 63;
    const int m = lane & 15, q = lane >> 4;
    const int bid   = blockIdx.x;
    const int ks    = bid >> 5;         // 0..7
    const int bb    = bid & 31;         // batch
    const int rbase = bb * 64;
    const int kg0   = ks * 32;

    const int kgl = lane >> 3;               // 0..7  A-staging granule col
    const int rr0 = wave * 8 + (lane & 7);   // A-staging row (i=0); +32 for i=1

    floatx4 acc[4][2];
#pragma unroll
    for (int rt = 0; rt < 4; ++rt)
#pragma unroll
        for (int hh = 0; hh < 2; ++hh)
            acc[rt][hh] = (floatx4){0.f, 0.f, 0.f, 0.f};

    floatx4 va0, va1, vb0, vb1;  // staged x: rows rr0 / rr0+32, 8 k each

#define LOAD_A(c)                                                             \
    {                                                                         \
        const int k_ = ks * 256 + (c) * 64 + kgl * 8;                         \
        const float* px_ = x + (size_t)(rbase + rr0) * 2000 + k_;             \
        if (k_ < 2000) {                                                      \
            va0 = *(const floatx4*)px_;                                       \
            va1 = *(const floatx4*)(px_ + 4);                                 \
            vb0 = *(const floatx4*)(px_ + 64000);                             \
            vb1 = *(const floatx4*)(px_ + 64004);                             \
        } else {                                                              \
            va0 = va1 = vb0 = vb1 = (floatx4){0.f, 0.f, 0.f, 0.f};            \
        }                                                                     \
    }

#define WRITE_A(c)                                                            \
    {                                                                         \
        unsigned char* sb_ = smem[(c) & 1];                                   \
        uintx4 g0_, g1_;                                                      \
        g0_.x = pk2(va0.x, va0.y); g0_.y = pk2(va0.z, va0.w);                 \
        g0_.z = pk2(va1.x, va1.y); g0_.w = pk2(va1.z, va1.w);                 \
        g1_.x = pk2(vb0.x, vb0.y); g1_.y = pk2(vb0.z, vb0.w);                 \
        g1_.z = pk2(vb1.x, vb1.y); g1_.w = pk2(vb1.z, vb1.w);                 \
        *(uintx4*)(sb_ + kgl * 1024 + rr0 * 16) = g0_;                        \
        *(uintx4*)(sb_ + kgl * 1024 + (rr0 + 32) * 16) = g1_;                 \
    }

#define ISSUE_B(c)                                                            \
    {                                                                         \
        unsigned char* sb_ = smem[(c) & 1];                                   \
        const int ckg_ = kg0 + (c) * 8;                                       \
        for (int j = wave; j < 16; j += 4) {                                  \
            const int kb_ = j >> 1, hf_ = j & 1;                              \
            gl_lds16(wt + ((size_t)(ckg_ + kb_) * 128 + hf_ * 64 + lane) * 8, \
                     sb_ + 8192 + kb_ * 2048 + hf_ * 1024);                   \
        }                                                                     \
    }

    LOAD_A(0);
    ISSUE_B(0);

    // Build M granules (hi/lo) while chunk-0 loads are in flight.
    // Granule g: kg = g>>6 (m-group), n = g&63; value M[n][kg*8+j] =
    // Mtg[(kg*8+j)*64 + n]. hi = bf16(v), lo = bf16(v - hi).
#pragma unroll
    for (int s = 0; s < 2; ++s) {
        const int g  = t * 2 + s;
        const int kg = g >> 6, n = g & 63;
        float v[8];
#pragma unroll
        for (int j = 0; j < 8; ++j) v[j] = Mtg[(kg * 8 + j) * 64 + n];
        unsigned short hb[8];
#pragma unroll
        for (int j = 0; j < 8; ++j) hb[j] = f2bf(v[j]);
        uintx4 wh, wl;
        wh.x = (unsigned)hb[0] | ((unsigned)hb[1] << 16);
        wh.y = (unsigned)hb[2] | ((unsigned)hb[3] << 16);
        wh.z = (unsigned)hb[4] | ((unsigned)hb[5] << 16);
        wh.w = (unsigned)hb[6] | ((unsigned)hb[7] << 16);
        wl.x = pk2(v[0] - bf2f(hb[0]), v[1] - bf2f(hb[1]));
        wl.y = pk2(v[2] - bf2f(hb[2]), v[3] - bf2f(hb[3]));
        wl.z = pk2(v[4] - bf2f(hb[4]), v[5] - bf2f(hb[5]));
        wl.w = pk2(v[6] - bf2f(hb[6]), v[7] - bf2f(hb[7]));
        *(uintx4*)(mg + g * 16)        = wh;
        *(uintx4*)(mg + 8192 + g * 16) = wl;
    }

    for (int c = 0; c < 4; ++c) {
        __builtin_amdgcn_s_waitcnt(0);   // own A regs + B DMA drained
        WRITE_A(c);                      // bf16 granules into buf c&1
        if (c < 3) {                     // overlap next chunk's HBM latency
            LOAD_A(c + 1);
            ISSUE_B(c + 1);
        }
        __syncthreads();                 // all waves' A writes + B DMA published
        const unsigned char* sb = smem[c & 1];
#pragma unroll
        for (int p = 0; p < 2; ++p) {
            shortx8 a[4];
#pragma unroll
            for (int rt = 0; rt < 4; ++rt)
                a[rt] = *(const shortx8*)(sb + (p * 4 + q) * 1024 + (rt * 16 + m) * 16);
            shortx8 bbf[2];
#pragma unroll
            for (int hh = 0; hh < 2; ++hh)
                bbf[hh] = *(const shortx8*)(sb + 8192 + (p * 4 + q) * 2048 +
                                            ((wave + hh * 4) * 16 + m) * 16);
#pragma unroll
            for (int rt = 0; rt < 4; ++rt)
#pragma unroll
                for (int hh = 0; hh < 2; ++hh)
                    acc[rt][hh] = __builtin_amdgcn_mfma_f32_16x16x32_bf16(
                        a[rt], bbf[hh], acc[rt][hh], 0, 0, 0);
        }
        __syncthreads();                 // all reads of buf c done before reuse
    }
#undef LOAD_A
#undef WRITE_A
#undef ISSUE_B

    // ---- fused M-apply epilogue -------------------------------------------
    // Stage partial z (64 nodes x 128 h) as hi/lo bf16 granules (kg = node
    // group, h), aliasing the (now dead) staging buffers. Granule stride
    // padded to 129 slots to spread banks.
    unsigned char* zhi = smem[0];
    unsigned char* zlo = smem[1];
#pragma unroll
    for (int rt = 0; rt < 4; ++rt) {
        const int kg  = rt * 2 + (q >> 1);      // node group
        const int off = (q & 1) * 8;            // node sub-offset (4 bf16)
#pragma unroll
        for (int hh = 0; hh < 2; ++hh) {
            const int h = (wave + hh * 4) * 16 + m;
            const floatx4 a = acc[rt][hh];      // nodes kg*8+off/2 .. +3
            const unsigned short h0 = f2bf(a.x), h1 = f2bf(a.y),
                                 h2 = f2bf(a.z), h3 = f2bf(a.w);
            uintx2 wh, wl;
            wh.x = (unsigned)h0 | ((unsigned)h1 << 16);
            wh.y = (unsigned)h2 | ((unsigned)h3 << 16);
            wl.x = pk2(a.x - bf2f(h0), a.y - bf2f(h1));
            wl.y = pk2(a.z - bf2f(h2), a.w - bf2f(h3));
            const int base = (kg * 129 + h) * 16 + off;
            *(uintx2*)(zhi + base) = wh;
            *(uintx2*)(zlo + base) = wl;
        }
    }
    __syncthreads();

    // y_part = M @ z  via error-split bf16 MFMA (K=64 -> 2 k-steps).
    floatx4 acc2[4][2];
#pragma unroll
    for (int nt = 0; nt < 4; ++nt)
#pragma unroll
        for (int hh = 0; hh < 2; ++hh)
            acc2[nt][hh] = (floatx4){0.f, 0.f, 0.f, 0.f};

#pragma unroll
    for (int kst = 0; kst < 2; ++kst) {
        shortx8 ah[4], al[4];
#pragma unroll
        for (int nt = 0; nt < 4; ++nt) {
            const int ga = ((kst * 4 + q) * 64 + nt * 16 + m) * 16;
            ah[nt] = *(const shortx8*)(mg + ga);
            al[nt] = *(const shortx8*)(mg + 8192 + ga);
        }
        shortx8 bh[2], bl[2];
#pragma unroll
        for (int hh = 0; hh < 2; ++hh) {
            const int gb = ((kst * 4 + q) * 129 + (wave + hh * 4) * 16 + m) * 16;
            bh[hh] = *(const shortx8*)(zhi + gb);
            bl[hh] = *(const shortx8*)(zlo + gb);
        }
#pragma unroll
        for (int nt = 0; nt < 4; ++nt)
#pragma unroll
            for (int hh = 0; hh < 2; ++hh) {
                acc2[nt][hh] = __builtin_amdgcn_mfma_f32_16x16x32_bf16(
                    ah[nt], bh[hh], acc2[nt][hh], 0, 0, 0);
                acc2[nt][hh] = __builtin_amdgcn_mfma_f32_16x16x32_bf16(
                    ah[nt], bl[hh], acc2[nt][hh], 0, 0, 0);
                acc2[nt][hh] = __builtin_amdgcn_mfma_f32_16x16x32_bf16(
                    al[nt], bh[hh], acc2[nt][hh], 0, 0, 0);
            }
    }

    // Accumulate into y (bias pre-filled by prep). C/D: row n = q*4+v, col h.
    float* yb = y + (size_t)bb * 8192;
#pragma unroll
    for (int nt = 0; nt < 4; ++nt)
#pragma unroll
        for (int hh = 0; hh < 2; ++hh) {
            const int h = (wave + hh * 4) * 16 + m;
#pragma unroll
            for (int v = 0; v < 4; ++v) {
                const int n = nt * 16 + q * 4 + v;
                atomicAdd(yb + n * 128 + h, acc2[nt][hh][v]);
            }
        }
}

extern "C" void kernel_launch(void* const* d_in, const int* in_sizes, int n_in,
                              void* d_out, int out_size, void* d_ws, size_t ws_size,
                              hipStream_t stream) {
    const float* x    = (const float*)d_in[0];   // (2048, 2000) fp32 (flat view)
    const int*   ei   = (const int*)d_in[1];     // (2, 4096)
    const float* ew   = (const float*)d_in[2];   // (4096,)
    const float* W    = (const float*)d_in[3];   // (128, 2000) fp32
    const float* bias = (const float*)d_in[4];   // (128,)
    float* y = (float*)d_out;                    // (32, 64, 128) fp32

    float* Mt = (float*)d_ws;                            // 4096 f
    unsigned short* wt = (unsigned short*)(Mt + 4096);   // 256*128*8 bf16 (512 KB)

    prep<<<28, 512, 0, stream>>>(W, ei, ew, bias, wt, Mt, y);
    gemm_fused<<<256, 256, 0, stream>>>(x, wt, Mt, y);
}